// Round 3
// baseline (65.633 us; speedup 1.0000x reference)
//
#include <hip/hip_runtime.h>
#include <hip/hip_bf16.h>
#include <math.h>

// Inverse Radon backprojection, buffer-OOB + antipodal-pair version.
// sinogram: (B, N=180, W=512) fp32;  angles: (N,) degrees fp32
// output:   (B, 1, 512, 512) fp32
//
// Identities vs reference:
//  - buffer_load with num_records=512*4 returns 0 for OOB taps ==
//    reference's mask*gather (masks/clamps eliminated, no padded copy).
//  - yw = wy0*my0 + wy1*my1 == sat(iy+1) * sat(512-iy)  (fmed3 clamp).
//  - antipodal pixel (511-x, 511-y): ix' = 511-ix, iy' = 511-iy, and yw
//    is symmetric under iy -> 511-iy, so yw' == yw. One thread computes
//    both pixels, sharing trig, iy, and yw.

#define IRD_W 512
#define IRD_N 180

#if __has_builtin(__builtin_amdgcn_raw_buffer_load_f32)
#define IRD_USE_BUFFER 1
#else
#define IRD_USE_BUFFER 0
#endif

#if IRD_USE_BUFFER
typedef int v4i __attribute__((ext_vector_type(4)));

__device__ __forceinline__ v4i make_rsrc(const void* p, unsigned nbytes) {
    union { struct { const void* p; unsigned nr; unsigned fl; } s; v4i v; } u;
    u.s.p = p; u.s.nr = nbytes; u.s.fl = 0x00020000u;  // raw dword SRD word3
    return u.v;
}

__global__ __launch_bounds__(256) void iradon_pair_kernel(
    const float* __restrict__ sino,    // B*N*W
    const float* __restrict__ angles,  // N
    float* __restrict__ out,           // B*H*W
    int half_total)                    // B*H*W/2
{
    __shared__ float2 s_trig[IRD_N];   // {cos*255.5, sin*255.5}

    const int tid = threadIdx.x;
    const float h = 255.5f;            // 0.5*(W-1)
    if (tid < IRD_N) {
        float th = angles[tid] * 0.017453292519943295f;
        float sv, cv;
        sincosf(th, &sv, &cv);
        s_trig[tid] = make_float2(cv * h, sv * h);
    }
    __syncthreads();

    const int i = blockIdx.x * 256 + tid;
    if (i >= half_total) return;

    const int x = i & (IRD_W - 1);
    const int y = (i >> 9) & 255;                   // top-half row
    const int b_s = (int)((blockIdx.x * 256u) >> 17);  // batch, scalar (uniform)

    const float step = 2.0f / (float)(IRD_W - 1);
    const float xs = -1.0f + (float)x * step;
    const float ys = -1.0f + (float)y * step;

    const float* __restrict__ sb = sino + (size_t)b_s * (IRD_N * IRD_W);

    float accA = 0.0f, accB = 0.0f;

    #pragma unroll 4
    for (int n = 0; n < IRD_N; ++n) {
        const float2 t = s_trig[n];
        const float ch = t.x, sh = t.y;

        const float ix  = fmaf(ch, xs, fmaf(sh, ys, h));
        const float iy  = fmaf(ch, ys, fmaf(sh, -xs, h));
        const float ixm = 511.0f - ix;               // antipodal detector coord

        const v4i rsrc = make_rsrc(sb + n * IRD_W, IRD_W * 4);

        // pixel A taps (OOB -> 0 via SRD bounds)
        const float fA  = floorf(ix);
        const float w1A = ix - fA;
        const float w0A = 1.0f - w1A;
        const int   vA  = ((int)fA) << 2;
        const float g0A = __builtin_amdgcn_raw_buffer_load_f32(rsrc, vA, 0, 0);
        const float g1A = __builtin_amdgcn_raw_buffer_load_f32(rsrc, vA + 4, 0, 0);

        // pixel B taps
        const float fB  = floorf(ixm);
        const float w1B = ixm - fB;
        const float w0B = 1.0f - w1B;
        const int   vB  = ((int)fB) << 2;
        const float g0B = __builtin_amdgcn_raw_buffer_load_f32(rsrc, vB, 0, 0);
        const float g1B = __builtin_amdgcn_raw_buffer_load_f32(rsrc, vB + 4, 0, 0);

        // shared y-weight (symmetric under iy -> 511-iy)
        const float a  = __builtin_amdgcn_fmed3f(iy + 1.0f,   0.0f, 1.0f);
        const float bb = __builtin_amdgcn_fmed3f(512.0f - iy, 0.0f, 1.0f);
        const float yw = a * bb;

        accA = fmaf(fmaf(w1A, g1A, w0A * g0A), yw, accA);
        accB = fmaf(fmaf(w1B, g1B, w0B * g0B), yw, accB);
    }

    const int p1 = (b_s << 18) + (y << 9) + x;
    const int p2 = (b_s << 18) + ((511 - y) << 9) + (511 - x);
    out[p1] = accA * (1.0f / (float)IRD_N);
    out[p2] = accB * (1.0f / (float)IRD_N);
}
#endif  // IRD_USE_BUFFER

// Fallback (no buffer builtin): fully masked version, known-correct.
__global__ __launch_bounds__(256) void iradon_kernel(
    const float* __restrict__ sino,
    const float* __restrict__ angles,
    float* __restrict__ out,
    int total)
{
    __shared__ float s_cos[IRD_N];
    __shared__ float s_sin[IRD_N];

    const int tid = threadIdx.x;
    for (int n = tid; n < IRD_N; n += blockDim.x) {
        float th = angles[n] * 0.017453292519943295f;
        float sv, cv;
        sincosf(th, &sv, &cv);
        s_cos[n] = cv;
        s_sin[n] = sv;
    }
    __syncthreads();

    const int pix = blockIdx.x * blockDim.x + tid;
    if (pix >= total) return;

    const int W = IRD_W;
    const int x = pix & (W - 1);
    const int y = (pix >> 9) & (W - 1);
    const int b = pix >> 18;

    const float step = 2.0f / (float)(W - 1);
    const float xs = -1.0f + (float)x * step;
    const float ys = -1.0f + (float)y * step;
    const float half = 0.5f * (float)(W - 1);
    const float wmax = (float)(W - 1);

    const float* __restrict__ sb = sino + (size_t)b * IRD_N * W;

    float acc = 0.0f;
    for (int n = 0; n < IRD_N; ++n) {
        const float c = s_cos[n];
        const float s = s_sin[n];
        const float gx = c * xs + s * ys;
        const float gy = c * ys - s * xs;
        const float ix = (gx + 1.0f) * half;
        const float iy = (gy + 1.0f) * half;
        const float x0f = floorf(ix);
        const float wx1 = ix - x0f;
        const float wx0 = 1.0f - wx1;
        const float x1f = x0f + 1.0f;
        const float mx0 = (x0f >= 0.0f && x0f <= wmax) ? 1.0f : 0.0f;
        const float mx1 = (x1f >= 0.0f && x1f <= wmax) ? 1.0f : 0.0f;
        int x0i = (int)fminf(fmaxf(x0f, 0.0f), wmax);
        int x1i = (int)fminf(fmaxf(x1f, 0.0f), wmax);
        const float y0f = floorf(iy);
        const float wy1 = iy - y0f;
        const float wy0 = 1.0f - wy1;
        const float y1f = y0f + 1.0f;
        const float my0 = (y0f >= 0.0f && y0f <= wmax) ? 1.0f : 0.0f;
        const float my1 = (y1f >= 0.0f && y1f <= wmax) ? 1.0f : 0.0f;
        const float yw = wy0 * my0 + wy1 * my1;
        const float* __restrict__ row = sb + n * W;
        acc += (wx0 * mx0 * row[x0i] + wx1 * mx1 * row[x1i]) * yw;
    }
    out[pix] = acc * (1.0f / (float)IRD_N);
}

extern "C" void kernel_launch(void* const* d_in, const int* in_sizes, int n_in,
                              void* d_out, int out_size, void* d_ws, size_t ws_size,
                              hipStream_t stream) {
    const float* sino = (const float*)d_in[0];
    const float* angles = (const float*)d_in[1];
    float* out = (float*)d_out;

    const int total = out_size;        // B*1*H*W
    const int block = 256;

#if IRD_USE_BUFFER
    const int half_total = total >> 1;
    const int grid = (half_total + block - 1) / block;
    iradon_pair_kernel<<<grid, block, 0, stream>>>(sino, angles, out, half_total);
#else
    const int grid = (total + block - 1) / block;
    iradon_kernel<<<grid, block, 0, stream>>>(sino, angles, out, total);
#endif
}

// Round 6
// 33.380 us; speedup vs baseline: 1.9662x; 1.9662x over previous
//
#include <hip/hip_runtime.h>
#include <hip/hip_bf16.h>
#include <math.h>

// Inverse Radon backprojection: zero-padded rows + antipodal pixel pairing.
// sinogram: (B, N=180, W=512) fp32;  angles: (N,) degrees fp32
// output:   (B, 1, 512, 512) fp32
//
// Identities vs reference (all components individually validated):
//  - zero-padded sinogram rows (width 768, data at [128,640)) make
//    wx0*mx0*g0 + wx1*mx1*g1 == wx0*pad[x0] + wx1*pad[x0+1] exactly
//    (validated round 2, absmax 9.8e-4).
//  - yw = wy0*my0 + wy1*my1 == sat(iy+1) * sat(512-iy) (validated round 2).
//  - antipodal pixel (511-x, 511-y): ix' = 511-ix, iy' = 511-iy, and yw is
//    symmetric under iy -> 511-iy, so one thread computes both pixels,
//    sharing trig, iy, and yw. (Mirror is continuous math, err ~1e-4 px.)
//
// Round-5 lesson: raw buffer_load OOB-returns-0 with NEGATIVE voffset is
// unverified on gfx950 (suspected 32-bit wrap in the bounds check) — padded
// gather has no OOB at all: x0+128 in [22,745] strictly inside PADW=768.

#define IRD_W 512
#define IRD_N 180
#define PADW 768
#define POFF 128

__global__ __launch_bounds__(256) void iradon_prep_kernel(
    const float* __restrict__ sino,   // B*N*W
    float* __restrict__ pad,          // B*N*PADW
    int total)                        // B*N*PADW
{
    int i = blockIdx.x * blockDim.x + threadIdx.x;
    if (i >= total) return;
    int j = i % PADW;
    int row = i / PADW;               // b*N + n
    float v = 0.0f;
    int src = j - POFF;
    if (src >= 0 && src < IRD_W) v = sino[row * IRD_W + src];
    pad[i] = v;
}

__global__ __launch_bounds__(256) void iradon_pair_kernel(
    const float* __restrict__ pad,     // B*N*PADW, zero-padded
    const float* __restrict__ angles,  // N
    float* __restrict__ out,           // B*H*W
    int half_total)                    // B*H*W/2
{
    __shared__ float2 s_trig[IRD_N];   // {cos*255.5, sin*255.5}

    const int tid = threadIdx.x;
    const float h = 255.5f;            // 0.5*(W-1)
    if (tid < IRD_N) {
        float th = angles[tid] * 0.017453292519943295f;
        float sv, cv;
        sincosf(th, &sv, &cv);
        s_trig[tid] = make_float2(cv * h, sv * h);
    }
    __syncthreads();

    const int i = blockIdx.x * 256 + tid;
    if (i >= half_total) return;

    const int x = i & (IRD_W - 1);
    const int y = (i >> 9) & 255;                      // top-half row
    const int b_s = (int)((blockIdx.x * 256u) >> 17);  // batch, wave-uniform

    const float step = 2.0f / (float)(IRD_W - 1);
    const float xs = -1.0f + (float)x * step;
    const float ys = -1.0f + (float)y * step;

    const float* __restrict__ rowb =
        pad + (size_t)b_s * (IRD_N * PADW) + POFF;

    float accA = 0.0f, accB = 0.0f;

    #pragma unroll 4
    for (int n = 0; n < IRD_N; ++n) {
        const float2 t = s_trig[n];
        const float ch = t.x, sh = t.y;

        const float ix  = fmaf(ch, xs, fmaf(sh, ys, h));
        const float iy  = fmaf(ch, ys, fmaf(sh, -xs, h));
        const float ixm = 511.0f - ix;               // antipodal detector coord

        const float* __restrict__ r = rowb + n * PADW;

        // pixel A x-taps (padded row: indices always in-bounds)
        const float fA  = floorf(ix);
        const float w1A = ix - fA;
        const float w0A = 1.0f - w1A;
        const int   iA  = (int)fA;
        const float g0A = r[iA];
        const float g1A = r[iA + 1];

        // pixel B x-taps
        const float fB  = floorf(ixm);
        const float w1B = ixm - fB;
        const float w0B = 1.0f - w1B;
        const int   iB  = (int)fB;
        const float g0B = r[iB];
        const float g1B = r[iB + 1];

        // shared y-weight (symmetric under iy -> 511-iy)
        const float a  = __builtin_amdgcn_fmed3f(iy + 1.0f,   0.0f, 1.0f);
        const float bb = __builtin_amdgcn_fmed3f(512.0f - iy, 0.0f, 1.0f);
        const float yw = a * bb;

        accA = fmaf(fmaf(w1A, g1A, w0A * g0A), yw, accA);
        accB = fmaf(fmaf(w1B, g1B, w0B * g0B), yw, accB);
    }

    const int p1 = (b_s << 18) + (y << 9) + x;
    const int p2 = (b_s << 18) + ((511 - y) << 9) + (511 - x);
    out[p1] = accA * (1.0f / (float)IRD_N);
    out[p2] = accB * (1.0f / (float)IRD_N);
}

extern "C" void kernel_launch(void* const* d_in, const int* in_sizes, int n_in,
                              void* d_out, int out_size, void* d_ws, size_t ws_size,
                              hipStream_t stream) {
    const float* sino = (const float*)d_in[0];
    const float* angles = (const float*)d_in[1];
    float* out = (float*)d_out;

    const int total = out_size;                    // B*1*H*W
    const int B = total >> 18;                     // H*W == 2^18
    const int block = 256;

    float* pad = (float*)d_ws;                     // B*N*PADW floats
    const int ptotal = B * IRD_N * PADW;
    iradon_prep_kernel<<<(ptotal + block - 1) / block, block, 0, stream>>>(
        sino, pad, ptotal);

    const int half_total = total >> 1;
    const int grid = (half_total + block - 1) / block;
    iradon_pair_kernel<<<grid, block, 0, stream>>>(pad, angles, out, half_total);
}

// Round 7
// 28.040 us; speedup vs baseline: 2.3407x; 1.1904x over previous
//
#include <hip/hip_runtime.h>
#include <hip/hip_bf16.h>
#include <math.h>

// Inverse Radon backprojection: per-tile LDS angle-windows + antipodal pairing.
// sinogram: (B, N=180, W=512) fp32;  angles: (N,) degrees fp32
// output:   (B, 1, 512, 512) fp32
//
// Structure: one block = 16x16 tile of pixel PAIRS (pixel (x,y) in top half +
// antipodal (511-x,511-y)). ix = ch*xs + sh*ys + 255.5 is linear in (x,y)
// with per-pixel step <= 1, so the tile touches <= 15*sqrt(2)+3 ~ 24
// consecutive sinogram elements per angle per half -> stage 32-float windows
// (x2 halves) for all 180 angles in LDS (46 KB), zero-filling out-of-range
// elements (replaces the r6 prep kernel + padded workspace).
//
// Inner-loop identities (validated r2/r6):
//  - taps from zero-filled window == reference mask*gather exactly
//  - yw = sat(iy+1) * sat(512-iy)  (fmed3)
//  - mirror: ix' = 511-ix, yw' == yw;  rebase folded into fma addend:
//    ixr = fma(ch,xs, fma(sh,ys, 255.5-baseA)),  ixmr = (511-baseA-baseB)-ixr
//
// r6 lesson: kernel was ~2/3 VMEM-gather-bound (VALU cut moved time only
// 0.93x) -> gathers moved to conflict-free LDS ds_read2 (lanes span <= 24
// distinct stride-1 addresses < 32 banks).

#define IRD_W 512
#define IRD_N 180
#define WIN   32
#define IRD_STEP (2.0f / 511.0f)

__global__ __launch_bounds__(256) void iradon_tile_kernel(
    const float* __restrict__ sino,    // B*N*W
    const float* __restrict__ angles,  // N
    float* __restrict__ out)           // B*H*W
{
    __shared__ float4 s_c[IRD_N];            // {ch, sh, 255.5-baseA, 511-baseA-baseB}
    __shared__ int2   s_base[IRD_N];         // {baseA, baseB}
    __shared__ float  s_win[IRD_N][2 * WIN]; // [angle][A-window | B-window]

    const int tid = threadIdx.x;
    const int x0 = (blockIdx.x & 31) << 4;   // tile origin, top half
    const int y0 = (blockIdx.x >> 5) << 4;   // y0 in [0,256)
    const int b  = blockIdx.y;

    const float h = 255.5f;
    const float xs0 = -1.0f + (float)x0 * IRD_STEP;
    const float ys0 = -1.0f + (float)y0 * IRD_STEP;
    const float xs1 = xs0 + 15.0f * IRD_STEP;
    const float ys1 = ys0 + 15.0f * IRD_STEP;

    if (tid < IRD_N) {
        float th = angles[tid] * 0.017453292519943295f;
        float sv, cv;
        sincosf(th, &sv, &cv);
        const float ch = cv * h, sh = sv * h;
        // tile-corner extrema of ix (linear in x,y -> corners suffice)
        const float cx0 = ch * xs0, cx1 = ch * xs1;
        const float sy0 = sh * ys0, sy1 = sh * ys1;
        const float minA = fminf(cx0, cx1) + fminf(sy0, sy1) + h;
        const float maxA = fmaxf(cx0, cx1) + fmaxf(sy0, sy1) + h;
        const int baseA = (int)floorf(minA) - 1;
        const int baseB = (int)floorf(511.0f - maxA) - 1;
        s_c[tid] = make_float4(ch, sh, h - (float)baseA,
                               (float)(511 - baseA - baseB));
        s_base[tid] = make_int2(baseA, baseB);
    }
    __syncthreads();

    // Cooperative window staging: lanes 0-31 of each 64-slot group -> A window,
    // 32-63 -> B window. Coalesced 128B runs; OOB -> 0 (== reference masks).
    const float* __restrict__ sb = sino + (size_t)b * (IRD_N * IRD_W);
    for (int idx = tid; idx < IRD_N * 2 * WIN; idx += 256) {
        const int n    = idx >> 6;
        const int slot = idx & 63;
        const int base = (slot < WIN) ? s_base[n].x : s_base[n].y;
        const int src  = base + (slot & (WIN - 1));
        float v = 0.0f;
        if ((unsigned)src < IRD_W) v = sb[n * IRD_W + src];
        s_win[n][slot] = v;
    }
    __syncthreads();

    const int x = x0 + (tid & 15);
    const int y = y0 + (tid >> 4);
    const float xs = -1.0f + (float)x * IRD_STEP;
    const float ys = -1.0f + (float)y * IRD_STEP;

    float accA = 0.0f, accB = 0.0f;

    #pragma unroll 4
    for (int n = 0; n < IRD_N; ++n) {
        const float4 t = s_c[n];
        const float ch = t.x, sh = t.y;

        const float ixr  = fmaf(ch, xs, fmaf(sh, ys, t.z));   // ix - baseA
        const float iy   = fmaf(ch, ys, fmaf(sh, -xs, h));    // absolute
        const float ixmr = t.w - ixr;                         // (511-ix)-baseB

        const float fA  = floorf(ixr);
        const float w1A = ixr - fA;
        const int   iA  = (int)fA;            // in [1, 24] -> in-window

        const float fB  = floorf(ixmr);
        const float w1B = ixmr - fB;
        const int   iB  = (int)fB;            // in [1, 24]

        const float g0A = s_win[n][iA];
        const float g1A = s_win[n][iA + 1];
        const float g0B = s_win[n][WIN + iB];
        const float g1B = s_win[n][WIN + iB + 1];

        const float a  = __builtin_amdgcn_fmed3f(iy + 1.0f,   0.0f, 1.0f);
        const float bb = __builtin_amdgcn_fmed3f(512.0f - iy, 0.0f, 1.0f);
        const float yw = a * bb;

        accA = fmaf(fmaf(w1A, g1A - g0A, g0A), yw, accA);
        accB = fmaf(fmaf(w1B, g1B - g0B, g0B), yw, accB);
    }

    const int ob = b << 18;
    out[ob + (y << 9) + x]                   = accA * (1.0f / 180.0f);
    out[ob + ((511 - y) << 9) + (511 - x)]   = accB * (1.0f / 180.0f);
}

extern "C" void kernel_launch(void* const* d_in, const int* in_sizes, int n_in,
                              void* d_out, int out_size, void* d_ws, size_t ws_size,
                              hipStream_t stream) {
    const float* sino = (const float*)d_in[0];
    const float* angles = (const float*)d_in[1];
    float* out = (float*)d_out;

    const int B = out_size >> 18;            // H*W == 2^18
    dim3 grid(512, B > 0 ? B : 1);           // 32x16 tiles cover the top half
    iradon_tile_kernel<<<grid, 256, 0, stream>>>(sino, angles, out);
}

// Round 8
// 20.428 us; speedup vs baseline: 3.2130x; 1.3727x over previous
//
#include <hip/hip_runtime.h>
#include <hip/hip_bf16.h>
#include <math.h>

// Inverse Radon backprojection: LDS angle-windows + antipodal pairing +
// 4-way within-block angle split for occupancy.
// sinogram: (B, N=180, W=512) fp32;  angles: (N,) degrees fp32
// output:   (B, 1, 512, 512) fp32
//
// Structure: one block = 16x16 tile of pixel PAIRS, 1024 threads = 4 threads
// per pair; thread quarter q sums angles [45q, 45q+45), LDS tree-combine at
// the end (order-fixed -> deterministic). Grid 512 blocks -> 2 blocks/CU x 16
// waves = 32 waves/CU (r7 had 8: latency-bound at ~25% VALU issue).
//
// Windows: ix = ch*xs + sh*ys + 255.5 is linear in (x,y), tile span <= 24
// consecutive sinogram elements per angle per half -> 32-float windows (x2
// halves) staged once per block, zero-filled OOB (== reference masks).
//
// Inner-loop identities (validated r2/r6/r7):
//  - taps from zero-filled window == reference mask*gather exactly
//  - yw = sat(iy+1) * sat(512-iy)  (fmed3)
//  - mirror: ix' = 511-ix, yw' == yw;  rebase folded into fma addends:
//    ixr = fma(ch,xs, fma(sh,ys, 255.5-baseA)),  ixmr = (511-baseA-baseB)-ixr

#define IRD_W 512
#define IRD_N 180
#define WIN   32
#define QN    45                      // angles per thread-quarter
#define IRD_STEP (2.0f / 511.0f)

__global__ __launch_bounds__(1024, 8) void iradon_tile4_kernel(
    const float* __restrict__ sino,    // B*N*W
    const float* __restrict__ angles,  // N
    float* __restrict__ out)           // B*H*W
{
    __shared__ float4 s_c[IRD_N];            // {ch, sh, 255.5-baseA, 511-baseA-baseB}
    __shared__ int2   s_base[IRD_N];         // {baseA, baseB}
    __shared__ float  s_win[IRD_N][2 * WIN]; // [angle][A-window | B-window]
    __shared__ float  s_redA[3][256];        // quarter partials (q=1..3)
    __shared__ float  s_redB[3][256];

    const int tid = threadIdx.x;
    const int x0 = (blockIdx.x & 31) << 4;   // tile origin, top half
    const int y0 = (blockIdx.x >> 5) << 4;   // y0 in [0,256)
    const int b  = blockIdx.y;

    const float h = 255.5f;
    const float xs0 = -1.0f + (float)x0 * IRD_STEP;
    const float ys0 = -1.0f + (float)y0 * IRD_STEP;
    const float xs1 = xs0 + 15.0f * IRD_STEP;
    const float ys1 = ys0 + 15.0f * IRD_STEP;

    if (tid < IRD_N) {
        float th = angles[tid] * 0.017453292519943295f;
        float sv, cv;
        sincosf(th, &sv, &cv);
        const float ch = cv * h, sh = sv * h;
        // tile-corner extrema of ix (linear in x,y -> corners suffice)
        const float cx0 = ch * xs0, cx1 = ch * xs1;
        const float sy0 = sh * ys0, sy1 = sh * ys1;
        const float minA = fminf(cx0, cx1) + fminf(sy0, sy1) + h;
        const float maxA = fmaxf(cx0, cx1) + fmaxf(sy0, sy1) + h;
        const int baseA = (int)floorf(minA) - 1;
        const int baseB = (int)floorf(511.0f - maxA) - 1;
        s_c[tid] = make_float4(ch, sh, h - (float)baseA,
                               (float)(511 - baseA - baseB));
        s_base[tid] = make_int2(baseA, baseB);
    }
    __syncthreads();

    // Cooperative window staging: within each 64-slot group, lanes 0-31 -> A
    // window, 32-63 -> B window. Coalesced; OOB -> 0 (== reference masks).
    const float* __restrict__ sb = sino + (size_t)b * (IRD_N * IRD_W);
    for (int idx = tid; idx < IRD_N * 2 * WIN; idx += 1024) {
        const int n    = idx >> 6;
        const int slot = idx & 63;
        const int base = (slot < WIN) ? s_base[n].x : s_base[n].y;
        const int src  = base + (slot & (WIN - 1));
        float v = 0.0f;
        if ((unsigned)src < IRD_W) v = sb[n * IRD_W + src];
        s_win[n][slot] = v;
    }
    __syncthreads();

    const int p = tid & 255;                 // pixel slot in tile
    const int q = tid >> 8;                  // angle quarter 0..3
    const int x = x0 + (p & 15);
    const int y = y0 + (p >> 4);
    const float xs = -1.0f + (float)x * IRD_STEP;
    const float ys = -1.0f + (float)y * IRD_STEP;
    const float xsn = -xs;

    float accA = 0.0f, accB = 0.0f;

    const int n0 = q * QN;
    #pragma unroll 5
    for (int k = 0; k < QN; ++k) {
        const int n = n0 + k;
        const float4 t = s_c[n];
        const float ch = t.x, sh = t.y;

        const float ixr  = fmaf(ch, xs, fmaf(sh, ys, t.z));   // ix - baseA
        const float iy   = fmaf(ch, ys, fmaf(sh, xsn, h));    // absolute
        const float ixmr = t.w - ixr;                         // (511-ix)-baseB

        const float fA  = floorf(ixr);
        const float w1A = ixr - fA;
        const int   iA  = (int)fA;            // in [1, 24] -> in-window

        const float fB  = floorf(ixmr);
        const float w1B = ixmr - fB;
        const int   iB  = (int)fB;            // in [1, 24]

        const float g0A = s_win[n][iA];
        const float g1A = s_win[n][iA + 1];
        const float g0B = s_win[n][WIN + iB];
        const float g1B = s_win[n][WIN + iB + 1];

        const float a  = __builtin_amdgcn_fmed3f(iy + 1.0f,   0.0f, 1.0f);
        const float bb = __builtin_amdgcn_fmed3f(512.0f - iy, 0.0f, 1.0f);
        const float yw = a * bb;

        accA = fmaf(fmaf(w1A, g1A - g0A, g0A), yw, accA);
        accB = fmaf(fmaf(w1B, g1B - g0B, g0B), yw, accB);
    }

    if (q != 0) {
        s_redA[q - 1][p] = accA;
        s_redB[q - 1][p] = accB;
    }
    __syncthreads();

    if (q == 0) {
        accA = ((accA + s_redA[0][p]) + s_redA[1][p]) + s_redA[2][p];
        accB = ((accB + s_redB[0][p]) + s_redB[1][p]) + s_redB[2][p];
        const int ob = b << 18;
        out[ob + (y << 9) + x]                 = accA * (1.0f / 180.0f);
        out[ob + ((511 - y) << 9) + (511 - x)] = accB * (1.0f / 180.0f);
    }
}

extern "C" void kernel_launch(void* const* d_in, const int* in_sizes, int n_in,
                              void* d_out, int out_size, void* d_ws, size_t ws_size,
                              hipStream_t stream) {
    const float* sino = (const float*)d_in[0];
    const float* angles = (const float*)d_in[1];
    float* out = (float*)d_out;

    const int B = out_size >> 18;            // H*W == 2^18
    dim3 grid(512, B > 0 ? B : 1);           // 32x16 tiles cover the top half
    iradon_tile4_kernel<<<grid, 1024, 0, stream>>>(sino, angles, out);
}